// Round 8
// baseline (185.569 us; speedup 1.0000x reference)
//
#include <hip/hip_runtime.h>
#include <cstddef>
#include <cstdint>

typedef unsigned short u16;
typedef unsigned int   u32;
typedef short bf16x8 __attribute__((ext_vector_type(8)));
typedef float f32x4  __attribute__((ext_vector_type(4)));

#define B_    8
#define C_    512
#define HW_   1024
#define NHEAD 8
#define DH    64
#define GRP   32
#define CPG   16
#define O3    1536
#define COND  512
#define EPSV  1e-5f
#define LOG2E 1.4426950408889634f

// ---- workspace byte offsets ----
#define BO_AFFA  0x1000u     // 4096 f32
#define BO_AFFB  0x5000u     // 4096 f32
#define BO_WQ    0x10000u    // 786432 bf16
#define BO_WO    0x190000u   // 262144 bf16
#define BO_XT    0x210000u   // [n][p][c] bf16, 8MB
#define BO_Q     0xA10000u   // [n][h][p][d] bf16 (pre-scaled by 0.125*log2e)
#define BO_K     0x1210000u  // [n][h][p][d] bf16
#define BO_V     0x1A10000u  // [n][h][d][p] bf16
#define BO_Y     0x2210000u  // [n][p][c] bf16

__device__ __forceinline__ u16 f2bf(float f) {
    u32 u = __float_as_uint(f);
    u += 0x7FFFu + ((u >> 16) & 1u);
    return (u16)(u >> 16);
}
__device__ __forceinline__ u32 cvtpk_bf16(float lo, float hi) {
    u32 r;
    asm("v_cvt_pk_bf16_f32 %0, %1, %2" : "=v"(r) : "v"(lo), "v"(hi));
    return r;
}
__device__ __forceinline__ bf16x8 as_frag(uint4 v) {
    union { uint4 u; bf16x8 f; } c; c.u = v; return c.f;
}

// ---------------- 1. fused prep: weight bf16 convert + group stats + cond map ----------------
// 256 blocks; block (n = bid&7, g = bid>>3). Group g == the 16-channel chunk whose
// affine coeffs this block produces (CPG == 16).
__global__ __launch_bounds__(256) void prep_kernel(const float* __restrict__ x,
                                                   const float* __restrict__ cond,
                                                   const float* __restrict__ Wmap,
                                                   const float* __restrict__ bmap,
                                                   const float* __restrict__ wq,
                                                   const float* __restrict__ wo,
                                                   u16* __restrict__ wqb,
                                                   u16* __restrict__ wob,
                                                   float* __restrict__ affA,
                                                   float* __restrict__ affB) {
    const int bid = blockIdx.x;
    const int n = bid & 7, g = bid >> 3;
    const int c0 = g * CPG;
    const int t = threadIdx.x;

    // --- phase D: weight convert (this block's 1/256 slice: 1024 float4 quads) ---
    {
        const int qbase = bid * 1024;
#pragma unroll
        for (int kq = 0; kq < 4; ++kq) {
            int idx = qbase + kq * 256 + t;
            if (idx < 196608) {                        // 786432/4 quads of W_qkv
                float4 v = ((const float4*)wq)[idx];
                uint2 o;
                o.x = (u32)f2bf(v.x) | ((u32)f2bf(v.y) << 16);
                o.y = (u32)f2bf(v.z) | ((u32)f2bf(v.w) << 16);
                ((uint2*)wqb)[idx] = o;
            } else {
                int j = idx - 196608;                  // < 65536 quads of W_out
                float4 v = ((const float4*)wo)[j];
                uint2 o;
                o.x = (u32)f2bf(v.x) | ((u32)f2bf(v.y) << 16);
                o.y = (u32)f2bf(v.z) | ((u32)f2bf(v.w) << 16);
                ((uint2*)wob)[j] = o;
            }
        }
    }

    // --- phase A: group stats (16 ch x 1024 px) ---
    __shared__ float r1[256], r2[256];
    __shared__ float cs[COND];
    __shared__ float red[32];
    __shared__ float sstat[2];
    {
        const float4* base = (const float4*)(x + ((size_t)n * C_ + c0) * HW_);
        float s1 = 0.f, s2 = 0.f;
        for (int i = t; i < CPG * HW_ / 4; i += 256) {
            float4 v = base[i];
            s1 += v.x + v.y + v.z + v.w;
            s2 += v.x*v.x + v.y*v.y + v.z*v.z + v.w*v.w;
        }
        r1[t] = s1; r2[t] = s2;
        // cond row -> LDS (independent loads, same barrier covers both)
        cs[t]       = cond[n * COND + t];
        cs[t + 256] = cond[n * COND + t + 256];
        __syncthreads();
        for (int s = 128; s > 0; s >>= 1) {
            if (t < s) { r1[t] += r1[t + s]; r2[t] += r2[t + s]; }
            __syncthreads();
        }
        if (t == 0) {
            const float inv = 1.f / (CPG * HW_);
            float mean = r1[0] * inv;
            float var  = r2[0] * inv - mean * mean;
            sstat[0] = mean;
            sstat[1] = rsqrtf(var + EPSV);
        }
    }
    __syncthreads();

    // --- phase B: 32 map dot-products (8 threads each) ---
    {
        const int oi = t >> 3, part = t & 7;     // oi: [0,16)=scale ch, [16,32)=shift ch
        const int is_shift = oi >> 4, ci = oi & 15;
        const int row = is_shift * C_ + c0 + ci;
        const float* wrow = Wmap + (size_t)row * COND + part * 4;
        float acc = 0.f;
#pragma unroll
        for (int i = 0; i < 16; ++i) {
            float4 wv = *(const float4*)(wrow + i * 32);
            float4 c4 = *(const float4*)&cs[i * 32 + part * 4];
            acc = fmaf(wv.x, c4.x, acc);
            acc = fmaf(wv.y, c4.y, acc);
            acc = fmaf(wv.z, c4.z, acc);
            acc = fmaf(wv.w, c4.w, acc);
        }
        acc += __shfl_xor(acc, 1);
        acc += __shfl_xor(acc, 2);
        acc += __shfl_xor(acc, 4);
        if (part == 0) red[oi] = acc;
    }
    __syncthreads();
    if (t < 16) {
        float scale = red[t]      + bmap[c0 + t];
        float shift = red[16 + t] + bmap[C_ + c0 + t];
        float mean = sstat[0], rstd = sstat[1];
        float a = rstd * (scale + 1.f);
        float b = shift - mean * a;
        affA[n * C_ + c0 + t] = a;
        affB[n * C_ + c0 + t] = b;
    }
}

// ---------------- 2. x -> normed-x^T bf16  [n][p][c] ----------------
__global__ __launch_bounds__(256) void xt_kernel(const float* __restrict__ x,
                                                 const float* __restrict__ affA,
                                                 const float* __restrict__ affB,
                                                 u16* __restrict__ xt) {
    __shared__ float ts[64][65];
    const int t = threadIdx.x;
    const int n = blockIdx.z, c0 = blockIdx.y * 64, p0 = blockIdx.x * 64;
    {
        int cl = t >> 2, pq = t & 3;
        int c = c0 + cl;
        float a = affA[n * C_ + c], b = affB[n * C_ + c];
        const float* src = x + ((size_t)n * C_ + c) * HW_ + p0 + pq * 16;
#pragma unroll
        for (int ii = 0; ii < 4; ++ii) {
            float4 v = *(const float4*)(src + ii * 4);
            ts[cl][pq * 16 + ii * 4 + 0] = fmaf(v.x, a, b);
            ts[cl][pq * 16 + ii * 4 + 1] = fmaf(v.y, a, b);
            ts[cl][pq * 16 + ii * 4 + 2] = fmaf(v.z, a, b);
            ts[cl][pq * 16 + ii * 4 + 3] = fmaf(v.w, a, b);
        }
    }
    __syncthreads();
    {
        int pl = t >> 2, cq = t & 3;
        u16 us[16];
#pragma unroll
        for (int r = 0; r < 16; ++r) us[r] = f2bf(ts[cq * 16 + r][pl]);
        uint4 v0, v1;
        v0.x = (u32)us[0]  | ((u32)us[1]  << 16);
        v0.y = (u32)us[2]  | ((u32)us[3]  << 16);
        v0.z = (u32)us[4]  | ((u32)us[5]  << 16);
        v0.w = (u32)us[6]  | ((u32)us[7]  << 16);
        v1.x = (u32)us[8]  | ((u32)us[9]  << 16);
        v1.y = (u32)us[10] | ((u32)us[11] << 16);
        v1.z = (u32)us[12] | ((u32)us[13] << 16);
        v1.w = (u32)us[14] | ((u32)us[15] << 16);
        u16* dst = xt + ((size_t)n * HW_ + p0 + pl) * C_ + c0 + cq * 16;
        *(uint4*)dst = v0;
        *(uint4*)(dst + 8) = v1;
    }
}

// ---------------- 3. QKV GEMM (MFMA, LDS-staged via global_load_lds) ----------------
__global__ __launch_bounds__(256) void qkv_mfma(const u16* __restrict__ wqb,
                                                const float* __restrict__ bq,
                                                const u16* __restrict__ xt,
                                                u16* __restrict__ Qb,
                                                u16* __restrict__ Kb,
                                                u16* __restrict__ Vb) {
    __shared__ __attribute__((aligned(16))) char smem[40960];
    u16 (*As)[64] = (u16(*)[64])smem;                 // [128][64]
    u16 (*Bs)[64] = (u16(*)[64])(smem + 16384);       // [128][64]
    u16 (*tb)[64][80] = (u16(*)[64][80])smem;         // [4][64][80] (epilogue alias)

    const int t = threadIdx.x, lane = t & 63, w = t >> 6;
    const int wm = w >> 1, wn = w & 1;
    const int lr = lane & 15, lg = lane >> 4;
    const int b = blockIdx.x;                       // 768, XCD-affine decode
    const int n  = b & 7;
    const int px = (b >> 3) & 7;
    const int oy = b >> 6;                          // 0..11
    const int obase = oy * 128 + wm * 64;
    const int pbase = px * 128 + wn * 64;
    const int rsub = lane >> 3, csub = lane & 7;    // staging row / chunk
    const int schk = csub ^ rsub;                   // pre-swizzled source chunk

    f32x4 acc[4][4] = {};

    for (int k0 = 0; k0 < C_; k0 += 64) {
#pragma unroll
        for (int ii = 0; ii < 4; ++ii) {
            int rloc = w * 32 + ii * 8;             // 8 rows per call
            const u16* ga = wqb + (size_t)(oy * 128 + rloc + rsub) * C_ + k0 + schk * 8;
            __builtin_amdgcn_global_load_lds((const __attribute__((address_space(1))) void*)ga,
                                             (__attribute__((address_space(3))) void*)&As[rloc][0],
                                             16, 0, 0);
            const u16* gb = xt + (size_t)(n * HW_ + px * 128 + rloc + rsub) * C_ + k0 + schk * 8;
            __builtin_amdgcn_global_load_lds((const __attribute__((address_space(1))) void*)gb,
                                             (__attribute__((address_space(3))) void*)&Bs[rloc][0],
                                             16, 0, 0);
        }
        __syncthreads();                            // drains staging (vmcnt0) before reads
#pragma unroll
        for (int ks = 0; ks < 2; ++ks) {
            bf16x8 af[4], bfv[4];
#pragma unroll
            for (int f = 0; f < 4; ++f) {
                int ra = wm * 64 + f * 16 + lr;
                af[f] = as_frag(*(const uint4*)&As[ra][((ks * 4 + lg) ^ (ra & 7)) * 8]);
                int rb = wn * 64 + f * 16 + lr;
                bfv[f] = as_frag(*(const uint4*)&Bs[rb][((ks * 4 + lg) ^ (rb & 7)) * 8]);
            }
#pragma unroll
            for (int i = 0; i < 4; ++i)
#pragma unroll
                for (int j = 0; j < 4; ++j)
                    acc[i][j] = __builtin_amdgcn_mfma_f32_16x16x32_bf16(af[i], bfv[j], acc[i][j], 0, 0, 0);
        }
        __syncthreads();                            // reads done before next-tile staging
    }

    const int region = obase >> 9;            // 0=Q 1=K 2=V
    const int hsel = (obase & 511) >> 6;
    float bias[4][4];
#pragma unroll
    for (int i = 0; i < 4; ++i)
#pragma unroll
        for (int r = 0; r < 4; ++r) bias[i][r] = bq[obase + i * 16 + lg * 4 + r];

    if (region < 2) {
        const float sc = (region == 0) ? 0.125f * LOG2E : 1.0f;  // fold s^2*log2e into Q
        u16* dst = (region == 0) ? Qb : Kb;
#pragma unroll
        for (int i = 0; i < 4; ++i)
#pragma unroll
            for (int j = 0; j < 4; ++j) {
                uint2 v;
                v.x = (u32)f2bf((acc[i][j][0] + bias[i][0]) * sc) |
                      ((u32)f2bf((acc[i][j][1] + bias[i][1]) * sc) << 16);
                v.y = (u32)f2bf((acc[i][j][2] + bias[i][2]) * sc) |
                      ((u32)f2bf((acc[i][j][3] + bias[i][3]) * sc) << 16);
                *(uint2*)&tb[w][j * 16 + lr][i * 16 + lg * 4] = v;  // [p_local][o_local]
            }
        __syncthreads();
        const size_t gb = ((size_t)(n * NHEAD + hsel) * HW_ + pbase) * DH;
#pragma unroll
        for (int c = 0; c < 8; ++c) {
            uint4 v = *(const uint4*)&tb[w][lane][c * 8];
            *(uint4*)&dst[gb + (size_t)lane * DH + c * 8] = v;
        }
    } else {
#pragma unroll
        for (int i = 0; i < 4; ++i)
#pragma unroll
            for (int j = 0; j < 4; ++j) {
                int p = pbase + j * 16 + lr;
#pragma unroll
                for (int r = 0; r < 4; ++r) {
                    int d = i * 16 + lg * 4 + r;
                    Vb[((size_t)(n * NHEAD + hsel) * DH + d) * HW_ + p] =
                        f2bf(acc[i][j][r] + bias[i][r]);
                }
            }
    }
}

// ---------------- 4. flash attention (MFMA, 1024 blocks, 16 q-rows/wave, defer-max) ----------------
__global__ __launch_bounds__(256) void attn_mfma(const u16* __restrict__ Qb,
                                                 const u16* __restrict__ Kb,
                                                 const u16* __restrict__ Vb,
                                                 u16* __restrict__ Yb) {
    __shared__ __attribute__((aligned(16))) u16 Kt[2][64][64]; // [buf][k][d], chunk^(k&7)
    __shared__ __attribute__((aligned(16))) u16 Vt[2][64][64]; // [buf][d][k], chunk^(d&7)
    __shared__ __attribute__((aligned(16))) u16 Pt[4][16][64]; // per-wave [q][k], chunk^(q&7)
    const int t = threadIdx.x, lane = t & 63, w = t >> 6;
    const int lr = lane & 15, lg = lane >> 4;
    const int b = blockIdx.x;                      // 1024; same (n,h) stays on one XCD
    const int nh = (b & 7) * 8 + ((b >> 3) & 7);
    const int q0g = (b >> 6) * 64;                 // 16 q-tiles of 64
    const size_t base = (size_t)nh * (HW_ * DH);
    const int srow = lane >> 3, schk = (lane & 7) ^ srow;   // staging source swizzle

    // Q fragments (pre-scaled by s^2*log2e), 16 q-rows per wave
    bf16x8 qf[2];
    {
        const uint4* Q4 = (const uint4*)(Qb + base);
        int qrow = q0g + w * 16 + lr;
        qf[0] = as_frag(Q4[qrow * 8 + lg]);
        qf[1] = as_frag(Q4[qrow * 8 + 4 + lg]);
    }

    auto stage = [&](int bb, int k0) {
#pragma unroll
        for (int ii = 0; ii < 2; ++ii) {
            int rk = w * 16 + ii * 8;
            const u16* gk = Kb + base + (size_t)(k0 + rk + srow) * DH + schk * 8;
            __builtin_amdgcn_global_load_lds((const __attribute__((address_space(1))) void*)gk,
                                             (__attribute__((address_space(3))) void*)&Kt[bb][rk][0],
                                             16, 0, 0);
            const u16* gv = Vb + base + (size_t)(rk + srow) * HW_ + k0 + schk * 8;
            __builtin_amdgcn_global_load_lds((const __attribute__((address_space(1))) void*)gv,
                                             (__attribute__((address_space(3))) void*)&Vt[bb][rk][0],
                                             16, 0, 0);
        }
    };

    float m_i = -3e38f, l_i = 0.f;
    f32x4 accy[4] = {};

    int buf = 0;
    stage(0, 0);
    for (int kt = 0; kt < 16; ++kt) {
        __syncthreads();                       // drains staging of buf + fences prev reads
        if (kt < 15) stage(buf ^ 1, (kt + 1) * 64);

        // S^T = K Q^T : lane holds q = w*16+lr, k = nf*16+lg*4+r
        f32x4 st[4] = {};
#pragma unroll
        for (int nf = 0; nf < 4; ++nf) {
#pragma unroll
            for (int ks = 0; ks < 2; ++ks) {
                int kl = nf * 16 + lr;
                bf16x8 kf = as_frag(*(const uint4*)&Kt[buf][kl][(((ks * 4 + lg) ^ (kl & 7)) * 8)]);
                st[nf] = __builtin_amdgcn_mfma_f32_16x16x32_bf16(kf, qf[ks], st[nf], 0, 0, 0);
            }
        }
        // lane-local softmax (exp2 domain) with defer-max (THR=8)
        {
            float x0 = fmaxf(fmaxf(st[0][0], st[0][1]), fmaxf(st[0][2], st[0][3]));
            float x1 = fmaxf(fmaxf(st[1][0], st[1][1]), fmaxf(st[1][2], st[1][3]));
            float x2 = fmaxf(fmaxf(st[2][0], st[2][1]), fmaxf(st[2][2], st[2][3]));
            float x3 = fmaxf(fmaxf(st[3][0], st[3][1]), fmaxf(st[3][2], st[3][3]));
            float rm = fmaxf(fmaxf(x0, x1), fmaxf(x2, x3));
            rm = fmaxf(rm, __shfl_xor(rm, 16));
            rm = fmaxf(rm, __shfl_xor(rm, 32));
            float nm = fmaxf(m_i, rm);
            if (!__all(nm - m_i <= 8.f)) {     // rescale only when max grew
                float fct = exp2f(m_i - nm);
                l_i *= fct;
#pragma unroll
                for (int df = 0; df < 4; ++df)
#pragma unroll
                    for (int r = 0; r < 4; ++r) accy[df][r] *= fct;
                m_i = nm;
            }
#pragma unroll
            for (int nf = 0; nf < 4; ++nf)
#pragma unroll
                for (int r = 0; r < 4; ++r) st[nf][r] = exp2f(st[nf][r] - m_i);
            float s0 = (st[0][0] + st[0][1]) + (st[0][2] + st[0][3]);
            float s1 = (st[1][0] + st[1][1]) + (st[1][2] + st[1][3]);
            float s2 = (st[2][0] + st[2][1]) + (st[2][2] + st[2][3]);
            float s3 = (st[3][0] + st[3][1]) + (st[3][2] + st[3][3]);
            float rs = (s0 + s1) + (s2 + s3);
            rs += __shfl_xor(rs, 16);
            rs += __shfl_xor(rs, 32);
            l_i += rs;
            // pack P -> per-wave LDS, swizzled; k = nf*16+lg*4..+3, q = lr
#pragma unroll
            for (int nf = 0; nf < 4; ++nf) {
                u32 lo = cvtpk_bf16(st[nf][0], st[nf][1]);
                u32 hi = cvtpk_bf16(st[nf][2], st[nf][3]);
                int c = nf * 2 + (lg >> 1);
                *(uint2*)&Pt[w][lr][((c ^ (lr & 7)) * 8) + (lg & 1) * 4] = make_uint2(lo, hi);
            }
        }
        // PV: Y^T[d][q] += V^T[d][k] P^T[k][q]
#pragma unroll
        for (int ks = 0; ks < 2; ++ks) {
            bf16x8 pf = as_frag(*(const uint4*)&Pt[w][lr][(((ks * 4 + lg) ^ (lr & 7)) * 8)]);
#pragma unroll
            for (int df = 0; df < 4; ++df) {
                int dl = df * 16 + lr;
                bf16x8 vf = as_frag(*(const uint4*)&Vt[buf][dl][(((ks * 4 + lg) ^ (dl & 7)) * 8)]);
                accy[df] = __builtin_amdgcn_mfma_f32_16x16x32_bf16(vf, pf, accy[df], 0, 0, 0);
            }
        }
        buf ^= 1;
    }

    // epilogue: normalize, direct global write (lane holds d = df*16+lg*4..+3, q = lr)
    const int n = nh >> 3, h = nh & 7;
    {
        float inv = 1.f / l_i;
        int p = q0g + w * 16 + lr;
#pragma unroll
        for (int df = 0; df < 4; ++df) {
            u32 lo = cvtpk_bf16(accy[df][0] * inv, accy[df][1] * inv);
            u32 hi = cvtpk_bf16(accy[df][2] * inv, accy[df][3] * inv);
            *(uint2*)&Yb[((size_t)(n * HW_ + p)) * C_ + h * DH + df * 16 + lg * 4] =
                make_uint2(lo, hi);
        }
    }
}

// ---------------- 5. out-proj GEMM (MFMA, LDS-staged) + bias + residual ----------------
__global__ __launch_bounds__(256) void out_mfma(const u16* __restrict__ wob,
                                                const float* __restrict__ bo,
                                                const u16* __restrict__ yb,
                                                const float* __restrict__ inp,
                                                float* __restrict__ out) {
    __shared__ __attribute__((aligned(16))) u16 As[128][64];
    __shared__ __attribute__((aligned(16))) u16 Bs[128][64];
    const int t = threadIdx.x, lane = t & 63, w = t >> 6;
    const int wm = w >> 1, wn = w & 1, lr = lane & 15, lg = lane >> 4;
    const int b = blockIdx.x;                    // 256, XCD-affine decode
    const int n  = b & 7;
    const int px = (b >> 3) & 7;
    const int oy = b >> 6;                       // 0..3
    const int obase = oy * 128 + wm * 64;
    const int pbase = px * 128 + wn * 64;
    const int rsub = lane >> 3, csub = lane & 7;
    const int schk = csub ^ rsub;

    f32x4 acc[4][4] = {};

    for (int k0 = 0; k0 < C_; k0 += 64) {
#pragma unroll
        for (int ii = 0; ii < 4; ++ii) {
            int rloc = w * 32 + ii * 8;
            const u16* ga = wob + (size_t)(oy * 128 + rloc + rsub) * C_ + k0 + schk * 8;
            __builtin_amdgcn_global_load_lds((const __attribute__((address_space(1))) void*)ga,
                                             (__attribute__((address_space(3))) void*)&As[rloc][0],
                                             16, 0, 0);
            const u16* gb = yb + (size_t)(n * HW_ + px * 128 + rloc + rsub) * C_ + k0 + schk * 8;
            __builtin_amdgcn_global_load_lds((const __attribute__((address_space(1))) void*)gb,
                                             (__attribute__((address_space(3))) void*)&Bs[rloc][0],
                                             16, 0, 0);
        }
        __syncthreads();
#pragma unroll
        for (int ks = 0; ks < 2; ++ks) {
            bf16x8 af[4], bfv[4];
#pragma unroll
            for (int f = 0; f < 4; ++f) {
                int ra = wm * 64 + f * 16 + lr;
                af[f] = as_frag(*(const uint4*)&As[ra][((ks * 4 + lg) ^ (ra & 7)) * 8]);
                int rb = wn * 64 + f * 16 + lr;
                bfv[f] = as_frag(*(const uint4*)&Bs[rb][((ks * 4 + lg) ^ (rb & 7)) * 8]);
            }
#pragma unroll
            for (int i = 0; i < 4; ++i)
#pragma unroll
                for (int j = 0; j < 4; ++j)
                    acc[i][j] = __builtin_amdgcn_mfma_f32_16x16x32_bf16(af[i], bfv[j], acc[i][j], 0, 0, 0);
        }
        __syncthreads();
    }
#pragma unroll
    for (int i = 0; i < 4; ++i)
#pragma unroll
        for (int r = 0; r < 4; ++r) {
            int o = obase + i * 16 + lg * 4 + r;
            float bias = bo[o];
#pragma unroll
            for (int j = 0; j < 4; ++j) {
                int p = pbase + j * 16 + lr;
                size_t idx = ((size_t)n * C_ + o) * HW_ + p;
                out[idx] = acc[i][j][r] + bias + inp[idx];
            }
        }
}

extern "C" void kernel_launch(void* const* d_in, const int* in_sizes, int n_in,
                              void* d_out, int out_size, void* d_ws, size_t ws_size,
                              hipStream_t stream) {
    const float* input = (const float*)d_in[0];
    const float* cond  = (const float*)d_in[1];
    const float* Wqkv  = (const float*)d_in[2];
    const float* bqkv  = (const float*)d_in[3];
    const float* Wout  = (const float*)d_in[4];
    const float* bout  = (const float*)d_in[5];
    const float* Wmap  = (const float*)d_in[6];
    const float* bmap  = (const float*)d_in[7];
    float* out = (float*)d_out;

    char* wsb = (char*)d_ws;
    float* affA  = (float*)(wsb + BO_AFFA);
    float* affB  = (float*)(wsb + BO_AFFB);
    u16* wqb = (u16*)(wsb + BO_WQ);
    u16* wob = (u16*)(wsb + BO_WO);
    u16* xt  = (u16*)(wsb + BO_XT);
    u16* Qb  = (u16*)(wsb + BO_Q);
    u16* Kb  = (u16*)(wsb + BO_K);
    u16* Vb  = (u16*)(wsb + BO_V);
    u16* Yb  = (u16*)(wsb + BO_Y);

    prep_kernel<<<dim3(256), 256, 0, stream>>>(input, cond, Wmap, bmap, Wqkv, Wout,
                                               wqb, wob, affA, affB);
    xt_kernel<<<dim3(16, 8, 8), 256, 0, stream>>>(input, affA, affB, xt);
    qkv_mfma<<<dim3(768), 256, 0, stream>>>(wqb, bqkv, xt, Qb, Kb, Vb);
    attn_mfma<<<dim3(1024), 256, 0, stream>>>(Qb, Kb, Vb, Yb);
    out_mfma<<<dim3(256), 256, 0, stream>>>(wob, bout, Yb, input, out);
}

// Round 11
// 174.019 us; speedup vs baseline: 1.0664x; 1.0664x over previous
//
#include <hip/hip_runtime.h>
#include <cstddef>
#include <cstdint>

typedef unsigned short u16;
typedef unsigned int   u32;
typedef short bf16x8 __attribute__((ext_vector_type(8)));
typedef float f32x4  __attribute__((ext_vector_type(4)));

#define B_    8
#define C_    512
#define HW_   1024
#define NHEAD 8
#define DH    64
#define GRP   32
#define CPG   16
#define O3    1536
#define COND  512
#define EPSV  1e-5f
#define LOG2E 1.4426950408889634f

// ---- workspace byte offsets ----
#define BO_AFFA  0x1000u     // 4096 f32
#define BO_AFFB  0x5000u     // 4096 f32
#define BO_WQ    0x10000u    // 786432 bf16
#define BO_WO    0x190000u   // 262144 bf16
#define BO_XT    0x210000u   // [n][p][c] bf16, 8MB
#define BO_Q     0xA10000u   // [n][h][p][d] bf16 (pre-scaled by 0.125*log2e)
#define BO_K     0x1210000u  // [n][h][p][d] bf16
#define BO_V     0x1A10000u  // [n][h][d][p] bf16
#define BO_Y     0x2210000u  // [n][p][c] bf16

__device__ __forceinline__ u16 f2bf(float f) {
    u32 u = __float_as_uint(f);
    u += 0x7FFFu + ((u >> 16) & 1u);
    return (u16)(u >> 16);
}
__device__ __forceinline__ u32 cvtpk_bf16(float lo, float hi) {
    u32 r;
    asm("v_cvt_pk_bf16_f32 %0, %1, %2" : "=v"(r) : "v"(lo), "v"(hi));
    return r;
}
__device__ __forceinline__ bf16x8 as_frag(uint4 v) {
    union { uint4 u; bf16x8 f; } c; c.u = v; return c.f;
}

// ---------------- 1. fused prep: weight bf16 convert + group stats + cond map ----------------
__global__ __launch_bounds__(256) void prep_kernel(const float* __restrict__ x,
                                                   const float* __restrict__ cond,
                                                   const float* __restrict__ Wmap,
                                                   const float* __restrict__ bmap,
                                                   const float* __restrict__ wq,
                                                   const float* __restrict__ wo,
                                                   u16* __restrict__ wqb,
                                                   u16* __restrict__ wob,
                                                   float* __restrict__ affA,
                                                   float* __restrict__ affB) {
    const int bid = blockIdx.x;
    const int n = bid & 7, g = bid >> 3;
    const int c0 = g * CPG;
    const int t = threadIdx.x;

    // --- weight convert (this block's 1/256 slice) ---
    {
        const int qbase = bid * 1024;
#pragma unroll
        for (int kq = 0; kq < 4; ++kq) {
            int idx = qbase + kq * 256 + t;
            if (idx < 196608) {
                float4 v = ((const float4*)wq)[idx];
                uint2 o;
                o.x = (u32)f2bf(v.x) | ((u32)f2bf(v.y) << 16);
                o.y = (u32)f2bf(v.z) | ((u32)f2bf(v.w) << 16);
                ((uint2*)wqb)[idx] = o;
            } else {
                int j = idx - 196608;
                float4 v = ((const float4*)wo)[j];
                uint2 o;
                o.x = (u32)f2bf(v.x) | ((u32)f2bf(v.y) << 16);
                o.y = (u32)f2bf(v.z) | ((u32)f2bf(v.w) << 16);
                ((uint2*)wob)[j] = o;
            }
        }
    }

    // --- group stats ---
    __shared__ float r1[256], r2[256];
    __shared__ float cs[COND];
    __shared__ float red[32];
    __shared__ float sstat[2];
    {
        const float4* base = (const float4*)(x + ((size_t)n * C_ + c0) * HW_);
        float s1 = 0.f, s2 = 0.f;
        for (int i = t; i < CPG * HW_ / 4; i += 256) {
            float4 v = base[i];
            s1 += v.x + v.y + v.z + v.w;
            s2 += v.x*v.x + v.y*v.y + v.z*v.z + v.w*v.w;
        }
        r1[t] = s1; r2[t] = s2;
        cs[t]       = cond[n * COND + t];
        cs[t + 256] = cond[n * COND + t + 256];
        __syncthreads();
        for (int s = 128; s > 0; s >>= 1) {
            if (t < s) { r1[t] += r1[t + s]; r2[t] += r2[t + s]; }
            __syncthreads();
        }
        if (t == 0) {
            const float inv = 1.f / (CPG * HW_);
            float mean = r1[0] * inv;
            float var  = r2[0] * inv - mean * mean;
            sstat[0] = mean;
            sstat[1] = rsqrtf(var + EPSV);
        }
    }
    __syncthreads();

    // --- 32 map dot-products ---
    {
        const int oi = t >> 3, part = t & 7;
        const int is_shift = oi >> 4, ci = oi & 15;
        const int row = is_shift * C_ + c0 + ci;
        const float* wrow = Wmap + (size_t)row * COND + part * 4;
        float acc = 0.f;
#pragma unroll
        for (int i = 0; i < 16; ++i) {
            float4 wv = *(const float4*)(wrow + i * 32);
            float4 c4 = *(const float4*)&cs[i * 32 + part * 4];
            acc = fmaf(wv.x, c4.x, acc);
            acc = fmaf(wv.y, c4.y, acc);
            acc = fmaf(wv.z, c4.z, acc);
            acc = fmaf(wv.w, c4.w, acc);
        }
        acc += __shfl_xor(acc, 1);
        acc += __shfl_xor(acc, 2);
        acc += __shfl_xor(acc, 4);
        if (part == 0) red[oi] = acc;
    }
    __syncthreads();
    if (t < 16) {
        float scale = red[t]      + bmap[c0 + t];
        float shift = red[16 + t] + bmap[C_ + c0 + t];
        float mean = sstat[0], rstd = sstat[1];
        float a = rstd * (scale + 1.f);
        float b = shift - mean * a;
        affA[n * C_ + c0 + t] = a;
        affB[n * C_ + c0 + t] = b;
    }
}

// ---------------- 2. x -> normed-x^T bf16  [n][p][c] ----------------
__global__ __launch_bounds__(256) void xt_kernel(const float* __restrict__ x,
                                                 const float* __restrict__ affA,
                                                 const float* __restrict__ affB,
                                                 u16* __restrict__ xt) {
    __shared__ float ts[64][65];
    const int t = threadIdx.x;
    const int n = blockIdx.z, c0 = blockIdx.y * 64, p0 = blockIdx.x * 64;
    {
        int cl = t >> 2, pq = t & 3;
        int c = c0 + cl;
        float a = affA[n * C_ + c], b = affB[n * C_ + c];
        const float* src = x + ((size_t)n * C_ + c) * HW_ + p0 + pq * 16;
#pragma unroll
        for (int ii = 0; ii < 4; ++ii) {
            float4 v = *(const float4*)(src + ii * 4);
            ts[cl][pq * 16 + ii * 4 + 0] = fmaf(v.x, a, b);
            ts[cl][pq * 16 + ii * 4 + 1] = fmaf(v.y, a, b);
            ts[cl][pq * 16 + ii * 4 + 2] = fmaf(v.z, a, b);
            ts[cl][pq * 16 + ii * 4 + 3] = fmaf(v.w, a, b);
        }
    }
    __syncthreads();
    {
        int pl = t >> 2, cq = t & 3;
        u16 us[16];
#pragma unroll
        for (int r = 0; r < 16; ++r) us[r] = f2bf(ts[cq * 16 + r][pl]);
        uint4 v0, v1;
        v0.x = (u32)us[0]  | ((u32)us[1]  << 16);
        v0.y = (u32)us[2]  | ((u32)us[3]  << 16);
        v0.z = (u32)us[4]  | ((u32)us[5]  << 16);
        v0.w = (u32)us[6]  | ((u32)us[7]  << 16);
        v1.x = (u32)us[8]  | ((u32)us[9]  << 16);
        v1.y = (u32)us[10] | ((u32)us[11] << 16);
        v1.z = (u32)us[12] | ((u32)us[13] << 16);
        v1.w = (u32)us[14] | ((u32)us[15] << 16);
        u16* dst = xt + ((size_t)n * HW_ + p0 + pl) * C_ + c0 + cq * 16;
        *(uint4*)dst = v0;
        *(uint4*)(dst + 8) = v1;
    }
}

// ---------------- 3. QKV GEMM (MFMA, LDS-staged via global_load_lds) ----------------
__global__ __launch_bounds__(256) void qkv_mfma(const u16* __restrict__ wqb,
                                                const float* __restrict__ bq,
                                                const u16* __restrict__ xt,
                                                u16* __restrict__ Qb,
                                                u16* __restrict__ Kb,
                                                u16* __restrict__ Vb) {
    __shared__ __attribute__((aligned(16))) char smem[40960];
    u16 (*As)[64] = (u16(*)[64])smem;                 // [128][64]
    u16 (*Bs)[64] = (u16(*)[64])(smem + 16384);       // [128][64]
    u16 (*tb)[64][80] = (u16(*)[64][80])smem;         // [4][64][80] (epilogue alias)

    const int t = threadIdx.x, lane = t & 63, w = t >> 6;
    const int wm = w >> 1, wn = w & 1;
    const int lr = lane & 15, lg = lane >> 4;
    const int b = blockIdx.x;                       // 768, XCD-affine decode
    const int n  = b & 7;
    const int px = (b >> 3) & 7;
    const int oy = b >> 6;                          // 0..11
    const int obase = oy * 128 + wm * 64;
    const int pbase = px * 128 + wn * 64;
    const int rsub = lane >> 3, csub = lane & 7;
    const int schk = csub ^ rsub;

    f32x4 acc[4][4] = {};

    for (int k0 = 0; k0 < C_; k0 += 64) {
#pragma unroll
        for (int ii = 0; ii < 4; ++ii) {
            int rloc = w * 32 + ii * 8;
            const u16* ga = wqb + (size_t)(oy * 128 + rloc + rsub) * C_ + k0 + schk * 8;
            __builtin_amdgcn_global_load_lds((const __attribute__((address_space(1))) void*)ga,
                                             (__attribute__((address_space(3))) void*)&As[rloc][0],
                                             16, 0, 0);
            const u16* gb = xt + (size_t)(n * HW_ + px * 128 + rloc + rsub) * C_ + k0 + schk * 8;
            __builtin_amdgcn_global_load_lds((const __attribute__((address_space(1))) void*)gb,
                                             (__attribute__((address_space(3))) void*)&Bs[rloc][0],
                                             16, 0, 0);
        }
        __syncthreads();
#pragma unroll
        for (int ks = 0; ks < 2; ++ks) {
            bf16x8 af[4], bfv[4];
#pragma unroll
            for (int f = 0; f < 4; ++f) {
                int ra = wm * 64 + f * 16 + lr;
                af[f] = as_frag(*(const uint4*)&As[ra][((ks * 4 + lg) ^ (ra & 7)) * 8]);
                int rb = wn * 64 + f * 16 + lr;
                bfv[f] = as_frag(*(const uint4*)&Bs[rb][((ks * 4 + lg) ^ (rb & 7)) * 8]);
            }
#pragma unroll
            for (int i = 0; i < 4; ++i)
#pragma unroll
                for (int j = 0; j < 4; ++j)
                    acc[i][j] = __builtin_amdgcn_mfma_f32_16x16x32_bf16(af[i], bfv[j], acc[i][j], 0, 0, 0);
        }
        __syncthreads();
    }

    const int region = obase >> 9;            // 0=Q 1=K 2=V
    const int hsel = (obase & 511) >> 6;
    float bias[4][4];
#pragma unroll
    for (int i = 0; i < 4; ++i)
#pragma unroll
        for (int r = 0; r < 4; ++r) bias[i][r] = bq[obase + i * 16 + lg * 4 + r];

    if (region < 2) {
        const float sc = (region == 0) ? 0.125f * LOG2E : 1.0f;
        u16* dst = (region == 0) ? Qb : Kb;
#pragma unroll
        for (int i = 0; i < 4; ++i)
#pragma unroll
            for (int j = 0; j < 4; ++j) {
                uint2 v;
                v.x = (u32)f2bf((acc[i][j][0] + bias[i][0]) * sc) |
                      ((u32)f2bf((acc[i][j][1] + bias[i][1]) * sc) << 16);
                v.y = (u32)f2bf((acc[i][j][2] + bias[i][2]) * sc) |
                      ((u32)f2bf((acc[i][j][3] + bias[i][3]) * sc) << 16);
                *(uint2*)&tb[w][j * 16 + lr][i * 16 + lg * 4] = v;
            }
        __syncthreads();
        const size_t gb = ((size_t)(n * NHEAD + hsel) * HW_ + pbase) * DH;
#pragma unroll
        for (int c = 0; c < 8; ++c) {
            uint4 v = *(const uint4*)&tb[w][lane][c * 8];
            *(uint4*)&dst[gb + (size_t)lane * DH + c * 8] = v;
        }
    } else {
#pragma unroll
        for (int i = 0; i < 4; ++i)
#pragma unroll
            for (int j = 0; j < 4; ++j) {
                int p = pbase + j * 16 + lr;
#pragma unroll
                for (int r = 0; r < 4; ++r) {
                    int d = i * 16 + lg * 4 + r;
                    Vb[((size_t)(n * NHEAD + hsel) * DH + d) * HW_ + p] =
                        f2bf(acc[i][j][r] + bias[i][r]);
                }
            }
    }
}

// ---------------- 4. flash attention (r8 softmax + static-dbuf unroll + setprio) ----------------
__global__ __launch_bounds__(256) void attn_mfma(const u16* __restrict__ Qb,
                                                 const u16* __restrict__ Kb,
                                                 const u16* __restrict__ Vb,
                                                 u16* __restrict__ Yb) {
    __shared__ __attribute__((aligned(16))) u16 Kt[2][64][64]; // [buf][k][d], chunk^(k&7)
    __shared__ __attribute__((aligned(16))) u16 Vt[2][64][64]; // [buf][d][k], chunk^(d&7)
    __shared__ __attribute__((aligned(16))) u16 Pt[4][16][64]; // per-wave [q][k], chunk^(q&7)
    const int t = threadIdx.x, lane = t & 63, w = t >> 6;
    const int lr = lane & 15, lg = lane >> 4;
    const int b = blockIdx.x;                      // 1024; same (n,h) stays on one XCD
    const int nh = (b & 7) * 8 + ((b >> 3) & 7);
    const int q0g = (b >> 6) * 64;
    const size_t base = (size_t)nh * (HW_ * DH);
    const int srow = lane >> 3, schk = (lane & 7) ^ srow;

    // Q fragments (pre-scaled by s^2*log2e), 16 q-rows per wave
    bf16x8 qf[2];
    {
        const uint4* Q4 = (const uint4*)(Qb + base);
        int qrow = q0g + w * 16 + lr;
        qf[0] = as_frag(Q4[qrow * 8 + lg]);
        qf[1] = as_frag(Q4[qrow * 8 + 4 + lg]);
    }

    auto stage = [&](int bb, int k0) {
#pragma unroll
        for (int ii = 0; ii < 2; ++ii) {
            int rk = w * 16 + ii * 8;
            const u16* gk = Kb + base + (size_t)(k0 + rk + srow) * DH + schk * 8;
            __builtin_amdgcn_global_load_lds((const __attribute__((address_space(1))) void*)gk,
                                             (__attribute__((address_space(3))) void*)&Kt[bb][rk][0],
                                             16, 0, 0);
            const u16* gv = Vb + base + (size_t)(rk + srow) * HW_ + k0 + schk * 8;
            __builtin_amdgcn_global_load_lds((const __attribute__((address_space(1))) void*)gv,
                                             (__attribute__((address_space(3))) void*)&Vt[bb][rk][0],
                                             16, 0, 0);
        }
    };

    float m_i = -3e38f, l_i = 0.f;
    f32x4 accy[4] = {};

    // one K/V tile; bufc is a literal at each call site -> static LDS addressing
    auto tile = [&](int bufc, int ktile, bool do_stage) {
        __syncthreads();                       // drains staging of bufc + fences prev reads
        if (do_stage) stage(bufc ^ 1, (ktile + 1) * 64);

        // S^T = K Q^T : lane holds q = w*16+lr, k = nf*16+lg*4+r
        f32x4 st[4] = {};
        __builtin_amdgcn_s_setprio(1);
#pragma unroll
        for (int nf = 0; nf < 4; ++nf) {
#pragma unroll
            for (int ks = 0; ks < 2; ++ks) {
                int kl = nf * 16 + lr;
                bf16x8 kf = as_frag(*(const uint4*)&Kt[bufc][kl][(((ks * 4 + lg) ^ (kl & 7)) * 8)]);
                st[nf] = __builtin_amdgcn_mfma_f32_16x16x32_bf16(kf, qf[ks], st[nf], 0, 0, 0);
            }
        }
        __builtin_amdgcn_s_setprio(0);
        // lane-local softmax (exp2 domain) with defer-max (THR=8) — r8-green formulation
        {
            float x0 = fmaxf(fmaxf(st[0][0], st[0][1]), fmaxf(st[0][2], st[0][3]));
            float x1 = fmaxf(fmaxf(st[1][0], st[1][1]), fmaxf(st[1][2], st[1][3]));
            float x2 = fmaxf(fmaxf(st[2][0], st[2][1]), fmaxf(st[2][2], st[2][3]));
            float x3 = fmaxf(fmaxf(st[3][0], st[3][1]), fmaxf(st[3][2], st[3][3]));
            float rm = fmaxf(fmaxf(x0, x1), fmaxf(x2, x3));
            rm = fmaxf(rm, __shfl_xor(rm, 16));
            rm = fmaxf(rm, __shfl_xor(rm, 32));
            float nm = fmaxf(m_i, rm);
            if (!__all(nm - m_i <= 8.f)) {     // rescale only when max grew
                float fct = exp2f(m_i - nm);
                l_i *= fct;
#pragma unroll
                for (int df = 0; df < 4; ++df)
#pragma unroll
                    for (int r = 0; r < 4; ++r) accy[df][r] *= fct;
                m_i = nm;
            }
#pragma unroll
            for (int nf = 0; nf < 4; ++nf)
#pragma unroll
                for (int r = 0; r < 4; ++r) st[nf][r] = __builtin_amdgcn_exp2f(st[nf][r] - m_i);
            float s0 = (st[0][0] + st[0][1]) + (st[0][2] + st[0][3]);
            float s1 = (st[1][0] + st[1][1]) + (st[1][2] + st[1][3]);
            float s2 = (st[2][0] + st[2][1]) + (st[2][2] + st[2][3]);
            float s3 = (st[3][0] + st[3][1]) + (st[3][2] + st[3][3]);
            float rs = (s0 + s1) + (s2 + s3);
            rs += __shfl_xor(rs, 16);
            rs += __shfl_xor(rs, 32);
            l_i += rs;
            // pack P -> per-wave LDS, swizzled; k = nf*16+lg*4..+3, q = lr
#pragma unroll
            for (int nf = 0; nf < 4; ++nf) {
                u32 lo = cvtpk_bf16(st[nf][0], st[nf][1]);
                u32 hi = cvtpk_bf16(st[nf][2], st[nf][3]);
                int c = nf * 2 + (lg >> 1);
                *(uint2*)&Pt[w][lr][((c ^ (lr & 7)) * 8) + (lg & 1) * 4] = make_uint2(lo, hi);
            }
        }
        // PV: Y^T[d][q] += V^T[d][k] P^T[k][q]
        __builtin_amdgcn_s_setprio(1);
#pragma unroll
        for (int ks = 0; ks < 2; ++ks) {
            bf16x8 pf = as_frag(*(const uint4*)&Pt[w][lr][(((ks * 4 + lg) ^ (lr & 7)) * 8)]);
#pragma unroll
            for (int df = 0; df < 4; ++df) {
                int dl = df * 16 + lr;
                bf16x8 vf = as_frag(*(const uint4*)&Vt[bufc][dl][(((ks * 4 + lg) ^ (dl & 7)) * 8)]);
                accy[df] = __builtin_amdgcn_mfma_f32_16x16x32_bf16(vf, pf, accy[df], 0, 0, 0);
            }
        }
        __builtin_amdgcn_s_setprio(0);
    };

    stage(0, 0);
    for (int kt2 = 0; kt2 < 8; ++kt2) {
        tile(0, kt2 * 2, true);
        tile(1, kt2 * 2 + 1, kt2 < 7);
    }

    // epilogue: normalize, direct global write (lane holds d = df*16+lg*4..+3, q = lr)
    const int n = nh >> 3, h = nh & 7;
    {
        float inv = 1.f / l_i;
        int p = q0g + w * 16 + lr;
#pragma unroll
        for (int df = 0; df < 4; ++df) {
            u32 lo = cvtpk_bf16(accy[df][0] * inv, accy[df][1] * inv);
            u32 hi = cvtpk_bf16(accy[df][2] * inv, accy[df][3] * inv);
            *(uint2*)&Yb[((size_t)(n * HW_ + p)) * C_ + h * DH + df * 16 + lg * 4] =
                make_uint2(lo, hi);
        }
    }
}

// ---------------- 5. out-proj GEMM (MFMA, LDS-staged) + bias + residual ----------------
__global__ __launch_bounds__(256) void out_mfma(const u16* __restrict__ wob,
                                                const float* __restrict__ bo,
                                                const u16* __restrict__ yb,
                                                const float* __restrict__ inp,
                                                float* __restrict__ out) {
    __shared__ __attribute__((aligned(16))) u16 As[128][64];
    __shared__ __attribute__((aligned(16))) u16 Bs[128][64];
    const int t = threadIdx.x, lane = t & 63, w = t >> 6;
    const int wm = w >> 1, wn = w & 1, lr = lane & 15, lg = lane >> 4;
    const int b = blockIdx.x;
    const int n  = b & 7;
    const int px = (b >> 3) & 7;
    const int oy = b >> 6;
    const int obase = oy * 128 + wm * 64;
    const int pbase = px * 128 + wn * 64;
    const int rsub = lane >> 3, csub = lane & 7;
    const int schk = csub ^ rsub;

    f32x4 acc[4][4] = {};

    for (int k0 = 0; k0 < C_; k0 += 64) {
#pragma unroll
        for (int ii = 0; ii < 4; ++ii) {
            int rloc = w * 32 + ii * 8;
            const u16* ga = wob + (size_t)(oy * 128 + rloc + rsub) * C_ + k0 + schk * 8;
            __builtin_amdgcn_global_load_lds((const __attribute__((address_space(1))) void*)ga,
                                             (__attribute__((address_space(3))) void*)&As[rloc][0],
                                             16, 0, 0);
            const u16* gb = yb + (size_t)(n * HW_ + px * 128 + rloc + rsub) * C_ + k0 + schk * 8;
            __builtin_amdgcn_global_load_lds((const __attribute__((address_space(1))) void*)gb,
                                             (__attribute__((address_space(3))) void*)&Bs[rloc][0],
                                             16, 0, 0);
        }
        __syncthreads();
#pragma unroll
        for (int ks = 0; ks < 2; ++ks) {
            bf16x8 af[4], bfv[4];
#pragma unroll
            for (int f = 0; f < 4; ++f) {
                int ra = wm * 64 + f * 16 + lr;
                af[f] = as_frag(*(const uint4*)&As[ra][((ks * 4 + lg) ^ (ra & 7)) * 8]);
                int rb = wn * 64 + f * 16 + lr;
                bfv[f] = as_frag(*(const uint4*)&Bs[rb][((ks * 4 + lg) ^ (rb & 7)) * 8]);
            }
#pragma unroll
            for (int i = 0; i < 4; ++i)
#pragma unroll
                for (int j = 0; j < 4; ++j)
                    acc[i][j] = __builtin_amdgcn_mfma_f32_16x16x32_bf16(af[i], bfv[j], acc[i][j], 0, 0, 0);
        }
        __syncthreads();
    }
#pragma unroll
    for (int i = 0; i < 4; ++i)
#pragma unroll
        for (int r = 0; r < 4; ++r) {
            int o = obase + i * 16 + lg * 4 + r;
            float bias = bo[o];
#pragma unroll
            for (int j = 0; j < 4; ++j) {
                int p = pbase + j * 16 + lr;
                size_t idx = ((size_t)n * C_ + o) * HW_ + p;
                out[idx] = acc[i][j][r] + bias + inp[idx];
            }
        }
}

extern "C" void kernel_launch(void* const* d_in, const int* in_sizes, int n_in,
                              void* d_out, int out_size, void* d_ws, size_t ws_size,
                              hipStream_t stream) {
    const float* input = (const float*)d_in[0];
    const float* cond  = (const float*)d_in[1];
    const float* Wqkv  = (const float*)d_in[2];
    const float* bqkv  = (const float*)d_in[3];
    const float* Wout  = (const float*)d_in[4];
    const float* bout  = (const float*)d_in[5];
    const float* Wmap  = (const float*)d_in[6];
    const float* bmap  = (const float*)d_in[7];
    float* out = (float*)d_out;

    char* wsb = (char*)d_ws;
    float* affA  = (float*)(wsb + BO_AFFA);
    float* affB  = (float*)(wsb + BO_AFFB);
    u16* wqb = (u16*)(wsb + BO_WQ);
    u16* wob = (u16*)(wsb + BO_WO);
    u16* xt  = (u16*)(wsb + BO_XT);
    u16* Qb  = (u16*)(wsb + BO_Q);
    u16* Kb  = (u16*)(wsb + BO_K);
    u16* Vb  = (u16*)(wsb + BO_V);
    u16* Yb  = (u16*)(wsb + BO_Y);

    prep_kernel<<<dim3(256), 256, 0, stream>>>(input, cond, Wmap, bmap, Wqkv, Wout,
                                               wqb, wob, affA, affB);
    xt_kernel<<<dim3(16, 8, 8), 256, 0, stream>>>(input, affA, affB, xt);
    qkv_mfma<<<dim3(768), 256, 0, stream>>>(wqb, bqkv, xt, Qb, Kb, Vb);
    attn_mfma<<<dim3(1024), 256, 0, stream>>>(Qb, Kb, Vb, Yb);
    out_mfma<<<dim3(256), 256, 0, stream>>>(wob, bout, Yb, input, out);
}